// Round 7
// baseline (257.616 us; speedup 1.0000x reference)
//
#include <hip/hip_runtime.h>
#include <hip/hip_bf16.h>
#include <math.h>

#define B_ 64
#define T_ 2048
#define D_ 512
#define U_ 512
#define NT_ (B_ * T_)   // 131072 rows

typedef __attribute__((ext_vector_type(8))) short short8;
typedef __attribute__((ext_vector_type(4))) float f32x4;

// RNE f32 -> bf16
__device__ __forceinline__ unsigned int f2bf(float x) {
  unsigned int u = __float_as_uint(x);
  unsigned int r = u + 0x7fffu + ((u >> 16) & 1u);
  return r >> 16;
}

// fast tanh: 1 - 2/(e^{2x}+1)
__device__ __forceinline__ float tanh_fast(float x) {
  float e = __expf(2.f * x);
  return 1.f - 2.f * __builtin_amdgcn_rcpf(e + 1.f);
}

// ---------------- q_proj = query @ W1 + b1 : [64,512] ----------------
__global__ __launch_bounds__(256) void k_qproj(const float* __restrict__ query,
                                               const float* __restrict__ W1,
                                               const float* __restrict__ b1,
                                               float* __restrict__ qproj) {
  const int b = blockIdx.x;
  const int tid = threadIdx.x;
  __shared__ float q[D_];
  q[tid] = query[b * D_ + tid];
  q[tid + 256] = query[b * D_ + tid + 256];
  __syncthreads();
  float a0 = 0.f, a1 = 0.f;
#pragma unroll 8
  for (int d = 0; d < D_; d++) {
    float qd = q[d];
    a0 = fmaf(qd, W1[d * U_ + tid], a0);
    a1 = fmaf(qd, W1[d * U_ + tid + 256], a1);
  }
  qproj[b * U_ + tid] = a0 + b1[tid];
  qproj[b * U_ + tid + 256] = a1 + b1[tid + 256];
}

// ---------------- W2 [k][u] f32 -> w2t [u][k] bf16 ----------------
__global__ __launch_bounds__(256) void k_w2t(const float* __restrict__ W2,
                                             unsigned short* __restrict__ w2t) {
  __shared__ float tile[32][33];
  const int k0 = blockIdx.y * 32, u0 = blockIdx.x * 32;
  const int tx = threadIdx.x, ty = threadIdx.y;  // 32 x 8
#pragma unroll
  for (int r = 0; r < 4; r++)
    tile[ty + 8 * r][tx] = W2[(size_t)(k0 + ty + 8 * r) * U_ + (u0 + tx)];
  __syncthreads();
#pragma unroll
  for (int r = 0; r < 4; r++) {
    int u_l = ty + 8 * r, k_l = tx;
    w2t[(size_t)(u0 + u_l) * D_ + (k0 + k_l)] = (unsigned short)f2bf(tile[k_l][u_l]);
  }
}

// ---------------- fused score GEMM (col-quartered, high-TLP) ----------------
// grid (4, 2048): x = col-quarter (fastest -> same-row quarters dispatch together,
// L3 reuse of A), y = row-tile. Block 256 thr = 4 waves, each wave 64 rows x 32 cols.
// BK=32, A+B double-buffered (24.5 KB) -> 5 blocks/CU, 1 __syncthreads per K-step.
// Writes partial col-sums to part_score[cq][row]; softmax combines (bv dropped:
// softmax is shift-invariant).
__global__ __launch_bounds__(256, 5) void k_score(
    const float* __restrict__ values, const unsigned short* __restrict__ w2t,
    const float* __restrict__ qproj, const float* __restrict__ b2,
    const float* __restrict__ Wv,
    float* __restrict__ part_score, int* __restrict__ flg) {
  __shared__ __align__(16) char pool[24576];
  char* lsA = pool;             // 2 x 4KB  [row 0..63][32k], 64B rows, slot-swizzled
  char* lsB = pool + 8192;      // 2 x 8KB  [col 0..127][32k]
  float* red = (float*)pool;    // epilogue alias [64 rows][4 waves]

  const int tid = threadIdx.x;
  const int wn = tid >> 6;      // 0..3 col-wave
  const int lane = tid & 63;
  const int cl = lane & 15;
  const int kg = lane >> 4;     // 0..3
  const int cq = blockIdx.x;    // 0..3 col quarter
  const int m0 = blockIdx.y * 64;
  const int b = m0 >> 11;       // T = 2048

  // epilogue constants in registers
  float qp_r[2], wv_r[2];
#pragma unroll
  for (int fc = 0; fc < 2; fc++) {
    int u = cq * 128 + wn * 32 + fc * 16 + cl;
    qp_r[fc] = qproj[b * U_ + u] + b2[u];
    wv_r[fc] = Wv[u];
  }

  // A staging: thread -> (row, 8-f32 chunk)
  const int arow = tid >> 2;   // 0..63
  const int akq = tid & 3;     // 0..3
  const float* aptr = values + (size_t)(m0 + arow) * D_ + akq * 8;
  const unsigned awoff = (unsigned)(arow * 64) + ((unsigned)((akq ^ ((arow >> 1) & 3)) & 3) << 4);

  // B gll: 2 chunks r=0,1; local col lc = (tid>>2)+r*64, slot = tid&3 (pre-swz src)
  const int blc0 = tid >> 2;
  const int bslot = tid & 3;

  f32x4 acc[4][2];
#pragma unroll
  for (int i = 0; i < 4; i++)
#pragma unroll
    for (int j = 0; j < 2; j++) acc[i][j] = (f32x4){0.f, 0.f, 0.f, 0.f};

  unsigned rfb = 0;  // OR of (f32 bits)<<1 over this thread's A elements

  // ---- prologue: stage tile 0 ----
  {
    float4 a0 = *(const float4*)aptr;
    float4 a1 = *(const float4*)(aptr + 4);
#pragma unroll
    for (int r = 0; r < 2; r++) {
      int lc = blc0 + r * 64;
      int s = bslot ^ ((lc >> 1) & 3);
      const unsigned short* src = w2t + (size_t)(cq * 128 + lc) * D_ + s * 8;
      __builtin_amdgcn_global_load_lds(
          (const __attribute__((address_space(1))) unsigned int*)src,
          (__attribute__((address_space(3))) unsigned int*)(lsB + tid * 16 + r * 4096),
          16, 0, 0);
    }
    rfb |= (__float_as_uint(a0.x) | __float_as_uint(a0.y) | __float_as_uint(a0.z) |
            __float_as_uint(a0.w) | __float_as_uint(a1.x) | __float_as_uint(a1.y) |
            __float_as_uint(a1.z) | __float_as_uint(a1.w)) << 1;
    uint4 pk;
    pk.x = f2bf(a0.x) | (f2bf(a0.y) << 16);
    pk.y = f2bf(a0.z) | (f2bf(a0.w) << 16);
    pk.z = f2bf(a1.x) | (f2bf(a1.y) << 16);
    pk.w = f2bf(a1.z) | (f2bf(a1.w) << 16);
    *(uint4*)(lsA + awoff) = pk;
  }
  __syncthreads();  // tile 0 published

  // ---- main loop: 16 K-steps, 1 barrier per step ----
#pragma unroll 1
  for (int t = 0; t < 16; t++) {
    const int cur = t & 1, nxt = cur ^ 1;
    char* curA = lsA + cur * 4096;
    char* curB = lsB + cur * 8192;

    float4 a0, a1;
    if (t < 15) {
      const int kk = (t + 1) * 32;
      a0 = *(const float4*)(aptr + kk);
      a1 = *(const float4*)(aptr + kk + 4);
#pragma unroll
      for (int r = 0; r < 2; r++) {
        int lc = blc0 + r * 64;
        int s = bslot ^ ((lc >> 1) & 3);
        const unsigned short* src = w2t + (size_t)(cq * 128 + lc) * D_ + kk + s * 8;
        __builtin_amdgcn_global_load_lds(
            (const __attribute__((address_space(1))) unsigned int*)src,
            (__attribute__((address_space(3))) unsigned int*)(lsB + nxt * 8192 + tid * 16 + r * 4096),
            16, 0, 0);
      }
    }

    // compute tile t
    short8 af[4], bf[2];
#pragma unroll
    for (int fr = 0; fr < 4; fr++) {
      int row = fr * 16 + cl;
      af[fr] = *(const short8*)(curA + row * 64 + (((kg ^ ((row >> 1) & 3)) & 3) << 4));
    }
#pragma unroll
    for (int fc = 0; fc < 2; fc++) {
      int lc = wn * 32 + fc * 16 + cl;
      bf[fc] = *(const short8*)(curB + lc * 64 + (((kg ^ ((lc >> 1) & 3)) & 3) << 4));
    }
#pragma unroll
    for (int fr = 0; fr < 4; fr++)
#pragma unroll
      for (int fc = 0; fc < 2; fc++)
        acc[fr][fc] = __builtin_amdgcn_mfma_f32_16x16x32_bf16(af[fr], bf[fc], acc[fr][fc], 0, 0, 0);

    if (t < 15) {
      // compiler inserts vmcnt for a0/a1 here; glls keep flying
      rfb |= (__float_as_uint(a0.x) | __float_as_uint(a0.y) | __float_as_uint(a0.z) |
              __float_as_uint(a0.w) | __float_as_uint(a1.x) | __float_as_uint(a1.y) |
              __float_as_uint(a1.z) | __float_as_uint(a1.w)) << 1;
      uint4 pk;
      pk.x = f2bf(a0.x) | (f2bf(a0.y) << 16);
      pk.y = f2bf(a0.z) | (f2bf(a0.w) << 16);
      pk.z = f2bf(a1.x) | (f2bf(a1.y) << 16);
      pk.w = f2bf(a1.z) | (f2bf(a1.w) << 16);
      *(uint4*)(lsA + nxt * 4096 + awoff) = pk;   // A(t+1): buf free since barrier t-1
    }
    __syncthreads();  // publish tile t+1; drain (mostly-landed) glls
  }

  // ---- rowflag combine across the 4 stager threads of each row ----
  rfb |= __shfl_xor((int)rfb, 1, 64);
  rfb |= __shfl_xor((int)rfb, 2, 64);
  if (akq == 0) flg[m0 + arow] = (rfb != 0);  // all 4 quarters write same value

  // ---- epilogue: partial score over this quarter's 128 cols ----
  float ps[4][4];
#pragma unroll
  for (int fr = 0; fr < 4; fr++)
#pragma unroll
    for (int r = 0; r < 4; r++) ps[fr][r] = 0.f;
#pragma unroll
  for (int fc = 0; fc < 2; fc++) {
    float qpu = qp_r[fc], wvu = wv_r[fc];
#pragma unroll
    for (int fr = 0; fr < 4; fr++)
#pragma unroll
      for (int r = 0; r < 4; r++)
        ps[fr][r] = fmaf(tanh_fast(acc[fr][fc][r] + qpu), wvu, ps[fr][r]);
  }
  const int rgrp = lane >> 4;
#pragma unroll
  for (int fr = 0; fr < 4; fr++)
#pragma unroll
    for (int r = 0; r < 4; r++) {
      float v = ps[fr][r];
      v += __shfl_xor(v, 1, 64);
      v += __shfl_xor(v, 2, 64);
      v += __shfl_xor(v, 4, 64);
      v += __shfl_xor(v, 8, 64);
      if (cl == 0) red[(fr * 16 + rgrp * 4 + r) * 4 + wn] = v;
    }
  __syncthreads();
  if (tid < 64) {
    float s = red[tid * 4] + red[tid * 4 + 1] + red[tid * 4 + 2] + red[tid * 4 + 3];
    part_score[(size_t)cq * NT_ + m0 + tid] = s;
  }
}

// ---------------- masked softmax over T per batch (sums 4 partials) ----------------
__global__ __launch_bounds__(256) void k_softmax(const float* __restrict__ part,
                                                 const int* __restrict__ flg,
                                                 float* __restrict__ attn) {
  const int b = blockIdx.x, tid = threadIdx.x;
  float s[8];
  float m = -INFINITY;
#pragma unroll
  for (int j = 0; j < 8; j++) {
    int idx = b * T_ + tid + 256 * j;
    float v = part[idx] + part[NT_ + idx] + part[2 * NT_ + idx] + part[3 * NT_ + idx];
    if (!flg[idx]) v = -INFINITY;
    s[j] = v;
    m = fmaxf(m, v);
  }
#pragma unroll
  for (int o = 1; o < 64; o <<= 1) m = fmaxf(m, __shfl_xor(m, o, 64));
  __shared__ float redm[4], redsum[4];
  if ((tid & 63) == 0) redm[tid >> 6] = m;
  __syncthreads();
  m = fmaxf(fmaxf(redm[0], redm[1]), fmaxf(redm[2], redm[3]));
  float sum = 0.f;
#pragma unroll
  for (int j = 0; j < 8; j++) {
    s[j] = __expf(s[j] - m);
    sum += s[j];
  }
#pragma unroll
  for (int o = 1; o < 64; o <<= 1) sum += __shfl_xor(sum, o, 64);
  if ((tid & 63) == 0) redsum[tid >> 6] = sum;
  __syncthreads();
  sum = redsum[0] + redsum[1] + redsum[2] + redsum[3];
  float inv = 1.f / sum;
#pragma unroll
  for (int j = 0; j < 8; j++) attn[(size_t)b * T_ + tid + 256 * j] = s[j] * inv;
}

// ---------------- context partial: per (b, t-chunk of 128) ----------------
__global__ __launch_bounds__(128) void k_ctx_part(const float* __restrict__ values,
                                                  const float* __restrict__ attn,
                                                  float* __restrict__ part) {
  const int tc = blockIdx.x, b = blockIdx.y;
  const int tid = threadIdx.x;
  const float4* vp = (const float4*)(values + ((size_t)b * T_ + tc * 128) * D_);
  const float* ap = attn + (size_t)b * T_ + tc * 128;
  float4 acc = {0.f, 0.f, 0.f, 0.f};
#pragma unroll 4
  for (int t = 0; t < 128; t++) {
    float w = ap[t];
    float4 v = vp[(size_t)t * 128 + tid];
    acc.x = fmaf(w, v.x, acc.x);
    acc.y = fmaf(w, v.y, acc.y);
    acc.z = fmaf(w, v.z, acc.z);
    acc.w = fmaf(w, v.w, acc.w);
  }
  float4* pp = (float4*)(part + (size_t)(b * 16 + tc) * D_);
  pp[tid] = acc;
}

// ---------------- context reduce over 16 t-chunks ----------------
__global__ __launch_bounds__(256) void k_ctx_reduce(const float* __restrict__ part,
                                                    float* __restrict__ ctx) {
  const int gid = blockIdx.x * 256 + threadIdx.x;  // 0..32767
  const int b = gid >> 9, d = gid & 511;
  float s = 0.f;
#pragma unroll
  for (int tc = 0; tc < 16; tc++) s += part[(size_t)(b * 16 + tc) * D_ + d];
  ctx[gid] = s;
}

extern "C" void kernel_launch(void* const* d_in, const int* in_sizes, int n_in,
                              void* d_out, int out_size, void* d_ws, size_t ws_size,
                              hipStream_t stream) {
  const float* query  = (const float*)d_in[0];
  const float* values = (const float*)d_in[1];
  const float* W1     = (const float*)d_in[2];
  const float* b1     = (const float*)d_in[3];
  const float* W2     = (const float*)d_in[4];
  const float* b2     = (const float*)d_in[5];
  const float* Wv     = (const float*)d_in[6];
  // bv (d_in[7]) is mathematically irrelevant: softmax is shift-invariant.

  float* out_ctx = (float*)d_out;                 // [64,512]
  float* out_attn = out_ctx + B_ * D_;            // [64,2048]

  char* ws = (char*)d_ws;
  float* qproj          = (float*)ws;                           // 128 KB
  unsigned short* w2t   = (unsigned short*)(ws + (128 << 10));  // 512 KB
  float* part_score     = (float*)(ws + (640 << 10));           // 2 MB  [4][131072]
  int* flg              = (int*)(ws + (2688 << 10));            // 512 KB
  float* part           = (float*)(ws + (3200 << 10));          // 2 MB

  k_qproj<<<dim3(B_), dim3(256), 0, stream>>>(query, W1, b1, qproj);
  k_w2t<<<dim3(16, 16), dim3(32, 8), 0, stream>>>(W2, w2t);
  k_score<<<dim3(4, (B_ * T_) / 64), dim3(256), 0, stream>>>(values, w2t, qproj, b2, Wv,
                                                             part_score, flg);
  k_softmax<<<dim3(B_), dim3(256), 0, stream>>>(part_score, flg, out_attn);
  k_ctx_part<<<dim3(16, B_), dim3(128), 0, stream>>>(values, out_attn, part);
  k_ctx_reduce<<<dim3(128), dim3(256), 0, stream>>>(part, out_ctx);
}

// Round 8
// 229.340 us; speedup vs baseline: 1.1233x; 1.1233x over previous
//
#include <hip/hip_runtime.h>
#include <hip/hip_bf16.h>
#include <math.h>

#define B_ 64
#define T_ 2048
#define D_ 512
#define U_ 512
#define NT_ (B_ * T_)   // 131072 rows

typedef __attribute__((ext_vector_type(8))) short short8;
typedef __attribute__((ext_vector_type(4))) float f32x4;

// RNE f32 -> bf16
__device__ __forceinline__ unsigned int f2bf(float x) {
  unsigned int u = __float_as_uint(x);
  unsigned int r = u + 0x7fffu + ((u >> 16) & 1u);
  return r >> 16;
}

// fast tanh: 1 - 2/(e^{2x}+1)
__device__ __forceinline__ float tanh_fast(float x) {
  float e = __expf(2.f * x);
  return 1.f - 2.f * __builtin_amdgcn_rcpf(e + 1.f);
}

// ---------------- q_proj = query @ W1 + b1 : [64,512] ----------------
__global__ __launch_bounds__(256) void k_qproj(const float* __restrict__ query,
                                               const float* __restrict__ W1,
                                               const float* __restrict__ b1,
                                               float* __restrict__ qproj) {
  const int b = blockIdx.x;
  const int tid = threadIdx.x;
  __shared__ float q[D_];
  q[tid] = query[b * D_ + tid];
  q[tid + 256] = query[b * D_ + tid + 256];
  __syncthreads();
  float a0 = 0.f, a1 = 0.f;
#pragma unroll 8
  for (int d = 0; d < D_; d++) {
    float qd = q[d];
    a0 = fmaf(qd, W1[d * U_ + tid], a0);
    a1 = fmaf(qd, W1[d * U_ + tid + 256], a1);
  }
  qproj[b * U_ + tid] = a0 + b1[tid];
  qproj[b * U_ + tid + 256] = a1 + b1[tid + 256];
}

// ---------------- W2 [k][u] f32 -> w2t [u][k] bf16 ----------------
__global__ __launch_bounds__(256) void k_w2t(const float* __restrict__ W2,
                                             unsigned short* __restrict__ w2t) {
  __shared__ float tile[32][33];
  const int k0 = blockIdx.y * 32, u0 = blockIdx.x * 32;
  const int tx = threadIdx.x, ty = threadIdx.y;  // 32 x 8
#pragma unroll
  for (int r = 0; r < 4; r++)
    tile[ty + 8 * r][tx] = W2[(size_t)(k0 + ty + 8 * r) * U_ + (u0 + tx)];
  __syncthreads();
#pragma unroll
  for (int r = 0; r < 4; r++) {
    int u_l = ty + 8 * r, k_l = tx;
    w2t[(size_t)(u0 + u_l) * D_ + (k0 + k_l)] = (unsigned short)f2bf(tile[k_l][u_l]);
  }
}

// ---------------- fused score GEMM (col-quartered, XCD-coherent mapping) ----------------
// 1-D grid 8192. Decode (assuming XCD = blockIdx % 8 round-robin):
//   x = d&7, j = d>>3, q = j&3, m = (j>>2)*8 + x
// -> the 4 col-quarters of row-group m are consecutive dispatch slots on ONE XCD:
//    A row-tile (128KB) fetched once per XCD L2, reused by 4 blocks; B L2-resident.
// Block 256 thr = 4 waves, wave-tile 64x32; BK=32, A+B dbuf, 1 barrier/K-step;
// 24KB LDS, 6 blocks/CU.
__global__ __launch_bounds__(256, 6) void k_score(
    const float* __restrict__ values, const unsigned short* __restrict__ w2t,
    const float* __restrict__ qproj, const float* __restrict__ b2,
    const float* __restrict__ Wv,
    float* __restrict__ part_score, int* __restrict__ flg) {
  __shared__ __align__(16) char pool[24576];
  char* lsA = pool;             // 2 x 4KB  [row 0..63][32k], 64B rows, slot-swizzled
  char* lsB = pool + 8192;      // 2 x 8KB  [col 0..127][32k]
  float* red = (float*)pool;    // epilogue alias [64 rows][4 waves]

  const int tid = threadIdx.x;
  const int wn = tid >> 6;      // 0..3 col-wave
  const int lane = tid & 63;
  const int cl = lane & 15;
  const int kg = lane >> 4;     // 0..3
  // XCD-coherent decode
  const int d = blockIdx.x;
  const int j = d >> 3;
  const int cq = j & 3;                       // col quarter
  const int m0 = (((j >> 2) << 3) + (d & 7)) * 64;  // row-tile base
  const int b = m0 >> 11;       // T = 2048

  // epilogue constants in registers
  float qp_r[2], wv_r[2];
#pragma unroll
  for (int fc = 0; fc < 2; fc++) {
    int u = cq * 128 + wn * 32 + fc * 16 + cl;
    qp_r[fc] = qproj[b * U_ + u] + b2[u];
    wv_r[fc] = Wv[u];
  }

  // A staging: thread -> (row, 8-f32 chunk)
  const int arow = tid >> 2;   // 0..63
  const int akq = tid & 3;     // 0..3
  const float* aptr = values + (size_t)(m0 + arow) * D_ + akq * 8;
  const unsigned awoff = (unsigned)(arow * 64) + ((unsigned)((akq ^ ((arow >> 1) & 3)) & 3) << 4);

  // B gll: 2 chunks r=0,1; local col lc = (tid>>2)+r*64, slot = tid&3 (pre-swz src)
  const int blc0 = tid >> 2;
  const int bslot = tid & 3;

  f32x4 acc[4][2];
#pragma unroll
  for (int i = 0; i < 4; i++)
#pragma unroll
    for (int j2 = 0; j2 < 2; j2++) acc[i][j2] = (f32x4){0.f, 0.f, 0.f, 0.f};

  unsigned rfb = 0;  // OR of packed bf16 words over this thread's A elements

  // ---- prologue: stage tile 0 ----
  {
    float4 a0 = *(const float4*)aptr;
    float4 a1 = *(const float4*)(aptr + 4);
#pragma unroll
    for (int r = 0; r < 2; r++) {
      int lc = blc0 + r * 64;
      int s = bslot ^ ((lc >> 1) & 3);
      const unsigned short* src = w2t + (size_t)(cq * 128 + lc) * D_ + s * 8;
      __builtin_amdgcn_global_load_lds(
          (const __attribute__((address_space(1))) unsigned int*)src,
          (__attribute__((address_space(3))) unsigned int*)(lsB + tid * 16 + r * 4096),
          16, 0, 0);
    }
    uint4 pk;
    pk.x = f2bf(a0.x) | (f2bf(a0.y) << 16);
    pk.y = f2bf(a0.z) | (f2bf(a0.w) << 16);
    pk.z = f2bf(a1.x) | (f2bf(a1.y) << 16);
    pk.w = f2bf(a1.z) | (f2bf(a1.w) << 16);
    rfb |= pk.x | pk.y | pk.z | pk.w;
    *(uint4*)(lsA + awoff) = pk;
  }
  __syncthreads();  // tile 0 published

  // ---- main loop: 16 K-steps, 1 barrier per step ----
#pragma unroll 1
  for (int t = 0; t < 16; t++) {
    const int cur = t & 1, nxt = cur ^ 1;
    char* curA = lsA + cur * 4096;
    char* curB = lsB + cur * 8192;

    float4 a0, a1;
    if (t < 15) {
      const int kk = (t + 1) * 32;
      a0 = *(const float4*)(aptr + kk);
      a1 = *(const float4*)(aptr + kk + 4);
#pragma unroll
      for (int r = 0; r < 2; r++) {
        int lc = blc0 + r * 64;
        int s = bslot ^ ((lc >> 1) & 3);
        const unsigned short* src = w2t + (size_t)(cq * 128 + lc) * D_ + kk + s * 8;
        __builtin_amdgcn_global_load_lds(
            (const __attribute__((address_space(1))) unsigned int*)src,
            (__attribute__((address_space(3))) unsigned int*)(lsB + nxt * 8192 + tid * 16 + r * 4096),
            16, 0, 0);
      }
    }

    // compute tile t
    short8 af[4], bf[2];
#pragma unroll
    for (int fr = 0; fr < 4; fr++) {
      int row = fr * 16 + cl;
      af[fr] = *(const short8*)(curA + row * 64 + (((kg ^ ((row >> 1) & 3)) & 3) << 4));
    }
#pragma unroll
    for (int fc = 0; fc < 2; fc++) {
      int lc = wn * 32 + fc * 16 + cl;
      bf[fc] = *(const short8*)(curB + lc * 64 + (((kg ^ ((lc >> 1) & 3)) & 3) << 4));
    }
#pragma unroll
    for (int fr = 0; fr < 4; fr++)
#pragma unroll
      for (int fc = 0; fc < 2; fc++)
        acc[fr][fc] = __builtin_amdgcn_mfma_f32_16x16x32_bf16(af[fr], bf[fc], acc[fr][fc], 0, 0, 0);

    if (t < 15) {
      // compiler inserts vmcnt for a0/a1 here; glls keep flying
      uint4 pk;
      pk.x = f2bf(a0.x) | (f2bf(a0.y) << 16);
      pk.y = f2bf(a0.z) | (f2bf(a0.w) << 16);
      pk.z = f2bf(a1.x) | (f2bf(a1.y) << 16);
      pk.w = f2bf(a1.z) | (f2bf(a1.w) << 16);
      rfb |= pk.x | pk.y | pk.z | pk.w;
      *(uint4*)(lsA + nxt * 4096 + awoff) = pk;   // A(t+1): buf free since barrier t-1
    }
    __syncthreads();  // publish tile t+1; drain (mostly-landed) glls
  }

  // ---- rowflag combine across the 4 stager threads of each row ----
  rfb |= __shfl_xor((int)rfb, 1, 64);
  rfb |= __shfl_xor((int)rfb, 2, 64);
  if (akq == 0 && cq == 0) flg[m0 + arow] = (rfb != 0);

  // ---- epilogue: partial score over this quarter's 128 cols ----
  float ps[4][4];
#pragma unroll
  for (int fr = 0; fr < 4; fr++)
#pragma unroll
    for (int r = 0; r < 4; r++) ps[fr][r] = 0.f;
#pragma unroll
  for (int fc = 0; fc < 2; fc++) {
    float qpu = qp_r[fc], wvu = wv_r[fc];
#pragma unroll
    for (int fr = 0; fr < 4; fr++)
#pragma unroll
      for (int r = 0; r < 4; r++)
        ps[fr][r] = fmaf(tanh_fast(acc[fr][fc][r] + qpu), wvu, ps[fr][r]);
  }
  const int rgrp = lane >> 4;
#pragma unroll
  for (int fr = 0; fr < 4; fr++)
#pragma unroll
    for (int r = 0; r < 4; r++) {
      float v = ps[fr][r];
      v += __shfl_xor(v, 1, 64);
      v += __shfl_xor(v, 2, 64);
      v += __shfl_xor(v, 4, 64);
      v += __shfl_xor(v, 8, 64);
      if (cl == 0) red[(fr * 16 + rgrp * 4 + r) * 4 + wn] = v;
    }
  __syncthreads();
  if (tid < 64) {
    float s = red[tid * 4] + red[tid * 4 + 1] + red[tid * 4 + 2] + red[tid * 4 + 3];
    part_score[(size_t)cq * NT_ + m0 + tid] = s;
  }
}

// ---------------- masked softmax over T per batch (sums 4 partials) ----------------
__global__ __launch_bounds__(256) void k_softmax(const float* __restrict__ part,
                                                 const int* __restrict__ flg,
                                                 float* __restrict__ attn) {
  const int b = blockIdx.x, tid = threadIdx.x;
  float s[8];
  float m = -INFINITY;
#pragma unroll
  for (int j = 0; j < 8; j++) {
    int idx = b * T_ + tid + 256 * j;
    float v = part[idx] + part[NT_ + idx] + part[2 * NT_ + idx] + part[3 * NT_ + idx];
    if (!flg[idx]) v = -INFINITY;
    s[j] = v;
    m = fmaxf(m, v);
  }
#pragma unroll
  for (int o = 1; o < 64; o <<= 1) m = fmaxf(m, __shfl_xor(m, o, 64));
  __shared__ float redm[4], redsum[4];
  if ((tid & 63) == 0) redm[tid >> 6] = m;
  __syncthreads();
  m = fmaxf(fmaxf(redm[0], redm[1]), fmaxf(redm[2], redm[3]));
  float sum = 0.f;
#pragma unroll
  for (int j = 0; j < 8; j++) {
    s[j] = __expf(s[j] - m);
    sum += s[j];
  }
#pragma unroll
  for (int o = 1; o < 64; o <<= 1) sum += __shfl_xor(sum, o, 64);
  if ((tid & 63) == 0) redsum[tid >> 6] = sum;
  __syncthreads();
  sum = redsum[0] + redsum[1] + redsum[2] + redsum[3];
  float inv = 1.f / sum;
#pragma unroll
  for (int j = 0; j < 8; j++) attn[(size_t)b * T_ + tid + 256 * j] = s[j] * inv;
}

// ---------------- context partial: per (b, t-chunk of 128) ----------------
__global__ __launch_bounds__(128) void k_ctx_part(const float* __restrict__ values,
                                                  const float* __restrict__ attn,
                                                  float* __restrict__ part) {
  const int tc = blockIdx.x, b = blockIdx.y;
  const int tid = threadIdx.x;
  const float4* vp = (const float4*)(values + ((size_t)b * T_ + tc * 128) * D_);
  const float* ap = attn + (size_t)b * T_ + tc * 128;
  float4 acc = {0.f, 0.f, 0.f, 0.f};
#pragma unroll 4
  for (int t = 0; t < 128; t++) {
    float w = ap[t];
    float4 v = vp[(size_t)t * 128 + tid];
    acc.x = fmaf(w, v.x, acc.x);
    acc.y = fmaf(w, v.y, acc.y);
    acc.z = fmaf(w, v.z, acc.z);
    acc.w = fmaf(w, v.w, acc.w);
  }
  float4* pp = (float4*)(part + (size_t)(b * 16 + tc) * D_);
  pp[tid] = acc;
}

// ---------------- context reduce over 16 t-chunks ----------------
__global__ __launch_bounds__(256) void k_ctx_reduce(const float* __restrict__ part,
                                                    float* __restrict__ ctx) {
  const int gid = blockIdx.x * 256 + threadIdx.x;  // 0..32767
  const int b = gid >> 9, d = gid & 511;
  float s = 0.f;
#pragma unroll
  for (int tc = 0; tc < 16; tc++) s += part[(size_t)(b * 16 + tc) * D_ + d];
  ctx[gid] = s;
}

extern "C" void kernel_launch(void* const* d_in, const int* in_sizes, int n_in,
                              void* d_out, int out_size, void* d_ws, size_t ws_size,
                              hipStream_t stream) {
  const float* query  = (const float*)d_in[0];
  const float* values = (const float*)d_in[1];
  const float* W1     = (const float*)d_in[2];
  const float* b1     = (const float*)d_in[3];
  const float* W2     = (const float*)d_in[4];
  const float* b2     = (const float*)d_in[5];
  const float* Wv     = (const float*)d_in[6];
  // bv (d_in[7]) is mathematically irrelevant: softmax is shift-invariant.

  float* out_ctx = (float*)d_out;                 // [64,512]
  float* out_attn = out_ctx + B_ * D_;            // [64,2048]

  char* ws = (char*)d_ws;
  float* qproj          = (float*)ws;                           // 128 KB
  unsigned short* w2t   = (unsigned short*)(ws + (128 << 10));  // 512 KB
  float* part_score     = (float*)(ws + (640 << 10));           // 2 MB  [4][131072]
  int* flg              = (int*)(ws + (2688 << 10));            // 512 KB
  float* part           = (float*)(ws + (3200 << 10));          // 2 MB

  k_qproj<<<dim3(B_), dim3(256), 0, stream>>>(query, W1, b1, qproj);
  k_w2t<<<dim3(16, 16), dim3(32, 8), 0, stream>>>(W2, w2t);
  k_score<<<dim3(8192), dim3(256), 0, stream>>>(values, w2t, qproj, b2, Wv,
                                                part_score, flg);
  k_softmax<<<dim3(B_), dim3(256), 0, stream>>>(part_score, flg, out_attn);
  k_ctx_part<<<dim3(16, B_), dim3(128), 0, stream>>>(values, out_attn, part);
  k_ctx_reduce<<<dim3(128), dim3(256), 0, stream>>>(part, out_ctx);
}

// Round 9
// 202.332 us; speedup vs baseline: 1.2732x; 1.1335x over previous
//
#include <hip/hip_runtime.h>
#include <hip/hip_bf16.h>
#include <math.h>

#define B_ 64
#define T_ 2048
#define D_ 512
#define U_ 512
#define NT_ (B_ * T_)   // 131072 rows

typedef __attribute__((ext_vector_type(8))) short short8;
typedef __attribute__((ext_vector_type(4))) float f32x4;

// RNE f32 -> bf16
__device__ __forceinline__ unsigned int f2bf(float x) {
  unsigned int u = __float_as_uint(x);
  unsigned int r = u + 0x7fffu + ((u >> 16) & 1u);
  return r >> 16;
}

// fast tanh: 1 - 2/(e^{2x}+1)
__device__ __forceinline__ float tanh_fast(float x) {
  float e = __expf(2.f * x);
  return 1.f - 2.f * __builtin_amdgcn_rcpf(e + 1.f);
}

// ---------------- q_proj = query @ W1 + b1 : [64,512] ----------------
__global__ __launch_bounds__(256) void k_qproj(const float* __restrict__ query,
                                               const float* __restrict__ W1,
                                               const float* __restrict__ b1,
                                               float* __restrict__ qproj) {
  const int b = blockIdx.x;
  const int tid = threadIdx.x;
  __shared__ float q[D_];
  q[tid] = query[b * D_ + tid];
  q[tid + 256] = query[b * D_ + tid + 256];
  __syncthreads();
  float a0 = 0.f, a1 = 0.f;
#pragma unroll 8
  for (int d = 0; d < D_; d++) {
    float qd = q[d];
    a0 = fmaf(qd, W1[d * U_ + tid], a0);
    a1 = fmaf(qd, W1[d * U_ + tid + 256], a1);
  }
  qproj[b * U_ + tid] = a0 + b1[tid];
  qproj[b * U_ + tid + 256] = a1 + b1[tid + 256];
}

// ---------------- W2 [k][u] f32 -> MFMA-fragment-tiled bf16 ----------------
// w2t2 layout: chunk = ut*16 + kc (ut: 16-col tile, kc: 32-k tile), 1KB per chunk:
//   ushort at chunk*512 + lane*8 + e  =  bf16(W2[kc*32 + (lane>>4)*8 + e][ut*16 + (lane&15)])
// A wave's B-fragment (16x16x32) = 64 lanes x 16B contiguous = one coalesced dwordx4.
__global__ __launch_bounds__(256) void k_w2t2(const float* __restrict__ W2,
                                              unsigned short* __restrict__ w2t2) {
  const int gid = blockIdx.x * 256 + threadIdx.x;  // 0..32767
  const int chunk = gid >> 6;                      // 0..511
  const int lane = gid & 63;
  const int ut = chunk >> 4, kc = chunk & 15;
  const int u = ut * 16 + (lane & 15);
  const int k0 = kc * 32 + (lane >> 4) * 8;
  uint4 pk;
  unsigned p[4];
#pragma unroll
  for (int i = 0; i < 4; i++) {
    float e0 = W2[(size_t)(k0 + 2 * i) * U_ + u];
    float e1 = W2[(size_t)(k0 + 2 * i + 1) * U_ + u];
    p[i] = f2bf(e0) | (f2bf(e1) << 16);
  }
  pk.x = p[0]; pk.y = p[1]; pk.z = p[2]; pk.w = p[3];
  *(uint4*)(w2t2 + (size_t)chunk * 512 + lane * 8) = pk;
}

// ---------------- fused score GEMM: barrier-free K-loop ----------------
// BM=64, BN=512, 8 waves (wave w: cols w*64..+64). A staged ONCE to LDS as bf16
// (16 subtiles of the round-8 proven 0-conflict layout), B read per-fragment from
// the tiled w2t2 (coalesced 1KB/instr, L2-resident). K-loop: 4 ds_read + 4 global
// + 16 MFMA per wave per step, ZERO barriers, zero staging VALU.
__global__ __launch_bounds__(512) void k_score(
    const float* __restrict__ values, const unsigned short* __restrict__ w2t2,
    const float* __restrict__ qproj, const float* __restrict__ b2,
    const float* __restrict__ Wv, float* __restrict__ scores) {
  __shared__ __align__(16) char pool[67840];
  char* lsA = pool;                       // 64KB: 16 x [64 rows][64B], slot-swizzled
  float* red = (float*)(pool + 65536);    // 2KB [64 rows][8 waves]
  int* flg = (int*)(pool + 67584);        // 256B

  const int tid = threadIdx.x;
  const int wid = tid >> 6;     // 0..7
  const int lane = tid & 63;
  const int cl = lane & 15;
  const int kg = lane >> 4;     // 0..3
  const int m0 = blockIdx.x * 64;
  const int b = m0 >> 11;       // T = 2048

  // epilogue constants -> registers
  float qp_r[4], wv_r[4];
#pragma unroll
  for (int fc = 0; fc < 4; fc++) {
    int u = wid * 64 + fc * 16 + cl;
    qp_r[fc] = qproj[b * U_ + u] + b2[u];
    wv_r[fc] = Wv[u];
  }

  // ---- pre-stage: all of A (64 rows x 512 k) f32 -> bf16 LDS, once ----
  const int arow = tid >> 3;   // 0..63
  const int akq = tid & 7;     // 0..7
  const float* aptr = values + (size_t)(m0 + arow) * D_;
  unsigned rfb = 0;
#pragma unroll
  for (int c = 0; c < 8; c++) {
    const int k0 = c * 64 + akq * 8;
    float4 a0 = *(const float4*)(aptr + k0);
    float4 a1 = *(const float4*)(aptr + k0 + 4);
    uint4 pk;
    pk.x = f2bf(a0.x) | (f2bf(a0.y) << 16);
    pk.y = f2bf(a0.z) | (f2bf(a0.w) << 16);
    pk.z = f2bf(a1.x) | (f2bf(a1.y) << 16);
    pk.w = f2bf(a1.z) | (f2bf(a1.w) << 16);
    rfb |= pk.x | pk.y | pk.z | pk.w;
    const int kc = k0 >> 5;
    const int slot = akq & 3;
    *(uint4*)(lsA + kc * 4096 + arow * 64 + ((slot ^ ((arow >> 1) & 3)) << 4)) = pk;
  }
  rfb |= __shfl_xor((int)rfb, 1, 64);
  rfb |= __shfl_xor((int)rfb, 2, 64);
  rfb |= __shfl_xor((int)rfb, 4, 64);
  if (akq == 0) flg[arow] = (rfb != 0);
  __syncthreads();  // the ONLY barrier before the epilogue

  // ---- K-loop: 16 steps, no barriers ----
  f32x4 acc[4][4];
#pragma unroll
  for (int i = 0; i < 4; i++)
#pragma unroll
    for (int j = 0; j < 4; j++) acc[i][j] = (f32x4){0.f, 0.f, 0.f, 0.f};

  const char* bbase = (const char*)w2t2 + (size_t)wid * 65536 + lane * 16;

#pragma unroll 2
  for (int t = 0; t < 16; t++) {
    short8 bf[4], af[4];
#pragma unroll
    for (int fc = 0; fc < 4; fc++)
      bf[fc] = *(const short8*)(bbase + fc * 16384 + t * 1024);
#pragma unroll
    for (int fr = 0; fr < 4; fr++) {
      int row = fr * 16 + cl;
      af[fr] = *(const short8*)(lsA + t * 4096 + row * 64 +
                                (((kg ^ ((row >> 1) & 3)) & 3) << 4));
    }
#pragma unroll
    for (int fr = 0; fr < 4; fr++)
#pragma unroll
      for (int fc = 0; fc < 4; fc++)
        acc[fr][fc] = __builtin_amdgcn_mfma_f32_16x16x32_bf16(af[fr], bf[fc], acc[fr][fc], 0, 0, 0);
  }

  // ---- epilogue: score = sum_u tanh(acc + qp[u]) * Wv[u] ----
  float ps[4][4];
#pragma unroll
  for (int fr = 0; fr < 4; fr++)
#pragma unroll
    for (int r = 0; r < 4; r++) ps[fr][r] = 0.f;
#pragma unroll
  for (int fc = 0; fc < 4; fc++) {
    float qpu = qp_r[fc], wvu = wv_r[fc];
#pragma unroll
    for (int fr = 0; fr < 4; fr++)
#pragma unroll
      for (int r = 0; r < 4; r++)
        ps[fr][r] = fmaf(tanh_fast(acc[fr][fc][r] + qpu), wvu, ps[fr][r]);
  }
#pragma unroll
  for (int fr = 0; fr < 4; fr++)
#pragma unroll
    for (int r = 0; r < 4; r++) {
      float v = ps[fr][r];
      v += __shfl_xor(v, 1, 64);
      v += __shfl_xor(v, 2, 64);
      v += __shfl_xor(v, 4, 64);
      v += __shfl_xor(v, 8, 64);
      if (cl == 0) red[(fr * 16 + kg * 4 + r) * 8 + wid] = v;
    }
  __syncthreads();
  if (tid < 64) {
    float s = 0.f;
#pragma unroll
    for (int w = 0; w < 8; w++) s += red[tid * 8 + w];
    if (!flg[tid]) s = -INFINITY;
    scores[m0 + tid] = s;
  }
}

// ---------------- softmax over T per batch ----------------
__global__ __launch_bounds__(256) void k_softmax(const float* __restrict__ scores,
                                                 float* __restrict__ attn) {
  const int b = blockIdx.x, tid = threadIdx.x;
  const float* srow = scores + (size_t)b * T_;
  float s[8];
  float m = -INFINITY;
#pragma unroll
  for (int j = 0; j < 8; j++) {
    s[j] = srow[tid + 256 * j];
    m = fmaxf(m, s[j]);
  }
#pragma unroll
  for (int o = 1; o < 64; o <<= 1) m = fmaxf(m, __shfl_xor(m, o, 64));
  __shared__ float redm[4], redsum[4];
  if ((tid & 63) == 0) redm[tid >> 6] = m;
  __syncthreads();
  m = fmaxf(fmaxf(redm[0], redm[1]), fmaxf(redm[2], redm[3]));
  float sum = 0.f;
#pragma unroll
  for (int j = 0; j < 8; j++) {
    s[j] = __expf(s[j] - m);
    sum += s[j];
  }
#pragma unroll
  for (int o = 1; o < 64; o <<= 1) sum += __shfl_xor(sum, o, 64);
  if ((tid & 63) == 0) redsum[tid >> 6] = sum;
  __syncthreads();
  sum = redsum[0] + redsum[1] + redsum[2] + redsum[3];
  float inv = 1.f / sum;
#pragma unroll
  for (int j = 0; j < 8; j++) attn[(size_t)b * T_ + tid + 256 * j] = s[j] * inv;
}

// ---------------- context partial: per (b, t-chunk of 128) ----------------
__global__ __launch_bounds__(128) void k_ctx_part(const float* __restrict__ values,
                                                  const float* __restrict__ attn,
                                                  float* __restrict__ part) {
  const int tc = blockIdx.x, b = blockIdx.y;
  const int tid = threadIdx.x;
  const float4* vp = (const float4*)(values + ((size_t)b * T_ + tc * 128) * D_);
  const float* ap = attn + (size_t)b * T_ + tc * 128;
  float4 acc = {0.f, 0.f, 0.f, 0.f};
#pragma unroll 4
  for (int t = 0; t < 128; t++) {
    float w = ap[t];
    float4 v = vp[(size_t)t * 128 + tid];
    acc.x = fmaf(w, v.x, acc.x);
    acc.y = fmaf(w, v.y, acc.y);
    acc.z = fmaf(w, v.z, acc.z);
    acc.w = fmaf(w, v.w, acc.w);
  }
  float4* pp = (float4*)(part + (size_t)(b * 16 + tc) * D_);
  pp[tid] = acc;
}

// ---------------- context reduce over 16 t-chunks ----------------
__global__ __launch_bounds__(256) void k_ctx_reduce(const float* __restrict__ part,
                                                    float* __restrict__ ctx) {
  const int gid = blockIdx.x * 256 + threadIdx.x;  // 0..32767
  const int b = gid >> 9, d = gid & 511;
  float s = 0.f;
#pragma unroll
  for (int tc = 0; tc < 16; tc++) s += part[(size_t)(b * 16 + tc) * D_ + d];
  ctx[gid] = s;
}

extern "C" void kernel_launch(void* const* d_in, const int* in_sizes, int n_in,
                              void* d_out, int out_size, void* d_ws, size_t ws_size,
                              hipStream_t stream) {
  const float* query  = (const float*)d_in[0];
  const float* values = (const float*)d_in[1];
  const float* W1     = (const float*)d_in[2];
  const float* b1     = (const float*)d_in[3];
  const float* W2     = (const float*)d_in[4];
  const float* b2     = (const float*)d_in[5];
  const float* Wv     = (const float*)d_in[6];
  // bv (d_in[7]) is mathematically irrelevant: softmax is shift-invariant.

  float* out_ctx = (float*)d_out;                 // [64,512]
  float* out_attn = out_ctx + B_ * D_;            // [64,2048]

  char* ws = (char*)d_ws;
  float* qproj          = (float*)ws;                           // 128 KB
  unsigned short* w2t2  = (unsigned short*)(ws + (128 << 10));  // 512 KB (tiled)
  float* scores         = (float*)(ws + (640 << 10));           // 512 KB
  float* part           = (float*)(ws + (1152 << 10));          // 2 MB

  k_qproj<<<dim3(B_), dim3(256), 0, stream>>>(query, W1, b1, qproj);
  k_w2t2<<<dim3(128), dim3(256), 0, stream>>>(W2, w2t2);
  k_score<<<dim3((B_ * T_) / 64), dim3(512), 0, stream>>>(values, w2t2, qproj, b2, Wv, scores);
  k_softmax<<<dim3(B_), dim3(256), 0, stream>>>(scores, out_attn);
  k_ctx_part<<<dim3(16, B_), dim3(128), 0, stream>>>(values, out_attn, part);
  k_ctx_reduce<<<dim3(128), dim3(256), 0, stream>>>(part, out_ctx);
}